// Round 12
// baseline (217.439 us; speedup 1.0000x reference)
//
#include <hip/hip_runtime.h>
#include <math.h>

#define BB 32
#define SS 1025
#define DD 64
#define HH 8
#define IN_D 8
#define NPATCH 1024
#define OUTD 9
#define EPSF 1e-5f
#define SD (SS*DD)        // 65600
#define SP 1056           // padded seq = 33*32
#define NQT 65            // ceil(1025/16) q-tiles
#define NCH 33            // 1056/32 t-chunks
#define VTROW 1064        // VT LDS row stride (shorts)
#define NTB 257           // blocks per batch for token/stat kernels
#define ZROW 1055         // guaranteed-zero K row (pad, zeroed by k_qkv)
#define QSTR 24           // q-tile stride between a slot's tiles (24 slots, grid 3)
#define LOG2_1E4 13.287712379549449f
#define ABLK (3 * HH)     // k_attn blocks per batch (grid x=3, y=HH)

typedef __attribute__((ext_vector_type(8))) short bf16x8;
typedef __attribute__((ext_vector_type(4))) float f32x4;
typedef __attribute__((ext_vector_type(4))) unsigned u32x4;

// fold softmax scale 1/sqrt(8) and exp->exp2 into Q
#define SCALE_LOG2E (0.35355339059327378f * 1.4426950408889634f)

#if __has_builtin(__builtin_amdgcn_exp2f)
__device__ __forceinline__ float exp2_fast(float x) { return __builtin_amdgcn_exp2f(x); }
#else
__device__ __forceinline__ float exp2_fast(float x) {
    float r; asm("v_exp_f32 %0, %1" : "=v"(r) : "v"(x)); return r;
}
#endif

__device__ __forceinline__ short f2bf(float f) {
    union { float f; unsigned u; } a; a.f = f;
    unsigned r = a.u + 0x7FFFu + ((a.u >> 16) & 1u);  // RNE
    return (short)(r >> 16);
}

// packed f32->bf16 (RNE); lo lands in the LOW short — matches A-frag short order.
__device__ __forceinline__ unsigned cvt_pk_bf16(float lo, float hi) {
    unsigned r;
    asm("v_cvt_pk_bf16_f32 %0, %1, %2" : "=v"(r) : "v"(lo), "v"(hi));
    return r;
}

// PV virtual-k permutation: for A-frag slot v = 8*quad + j, the P value the lane
// already holds in registers is S^T tile row t = 4*quad + (j&3) + 16*(j>>2).
// sigma(v) = bit-shuffle {b2,b4,b3,b1,b0} — bijective on [0,32). V is staged with
// the same permutation so A and B agree on k-order (MFMA k-order is arbitrary).
__device__ __forceinline__ int sigmaPV(int v) {
    return ((v & 24) >> 1) | (v & 3) | ((v & 4) << 2);
}

// ---------------- tokens = [cls; patches@w_map+b_map] + pos; per-block partial ln1 stats ----------------
// R21 (kept): powf libcall -> exp2 identity. R23: bx==0 also zeroes cnt2[b] (the
// k_attn last-block counter; must be kernel-zeroed per rep — harness fill poisons ws).
__global__ void k_tokens(const float* __restrict__ images, const float* __restrict__ w_map,
                         const float* __restrict__ b_map, const float* __restrict__ cls,
                         float* __restrict__ tokens, float* __restrict__ part1,
                         float* __restrict__ partq1, float* __restrict__ sum2,
                         float* __restrict__ sumsq2, unsigned* __restrict__ cnt2) {
    int b = blockIdx.y;
    int bx = blockIdx.x;
    int idx = bx * 256 + threadIdx.x;   // [0, SD)
    int tid = threadIdx.x;
    __shared__ float recip[64];
    __shared__ float wsred[8];
    if (tid < 64) {
        int j = tid;
        float div;
        if ((j & 1) == 0)
            div = exp2_fast((float)j * (LOG2_1E4 / 64.0f));
        else  // reference: 10000^(j-1)/64; overflow->inf -> recip 0 -> arg 0 -> cos=1 (matches f64)
            div = exp2_fast((float)(j - 1) * LOG2_1E4) * (1.0f / 64.0f);
        recip[j] = 1.0f / div;
    }
    __syncthreads();
    float lv = 0.f, lvv = 0.f;
    if (idx < SD) {
        int s = idx >> 6, j = idx & 63;
        float arg = (float)s * recip[j];
        float pv = (j & 1) ? __cosf(arg) : __sinf(arg);
        float v;
        if (s == 0) {
            v = cls[j];
        } else {
            const float* p = images + (size_t)b * (NPATCH * IN_D) + (size_t)(s - 1) * IN_D;
            float acc = b_map[j];
#pragma unroll
            for (int i = 0; i < IN_D; ++i) acc += p[i] * w_map[i * DD + j];
            v = acc;
        }
        v += pv;
        tokens[(size_t)b * SD + idx] = v;
        lv = v; lvv = v * v;
    }
    // wave64 shuffle reduce, then cross-wave combine (1 barrier)
    for (int off = 32; off > 0; off >>= 1) {
        lv += __shfl_down(lv, off, 64);
        lvv += __shfl_down(lvv, off, 64);
    }
    int wv = tid >> 6, ln = tid & 63;
    if (ln == 0) { wsred[wv] = lv; wsred[4 + wv] = lvv; }
    __syncthreads();
    if (tid == 0)  part1[b * NTB + bx]  = wsred[0] + wsred[1] + wsred[2] + wsred[3];
    if (tid == 64) partq1[b * NTB + bx] = wsred[4] + wsred[5] + wsred[6] + wsred[7];
    if (bx == 0) {          // zero the ln2 stat accumulators + last-block counter
        if (tid == 0) sum2[b] = 0.f;
        if (tid == 1) sumsq2[b] = 0.f;
        if (tid == 2) cnt2[b] = 0u;
    }
}

// ---------------- reduce ln1 partials once per batch ----------------
__global__ void k_stats(const float* __restrict__ part1, const float* __restrict__ partq1,
                        float* __restrict__ stats) {
    int b = blockIdx.x, tid = threadIdx.x;   // 256 thr
    float s = 0.f, ss = 0.f;
    for (int i = tid; i < NTB; i += 256) { s += part1[b * NTB + i]; ss += partq1[b * NTB + i]; }
    for (int off = 32; off > 0; off >>= 1) {
        s += __shfl_down(s, off, 64);
        ss += __shfl_down(ss, off, 64);
    }
    __shared__ float wsred[8];
    int wv = tid >> 6, ln = tid & 63;
    if (ln == 0) { wsred[wv] = s; wsred[4 + wv] = ss; }
    __syncthreads();
    if (tid == 0) {
        float t  = wsred[0] + wsred[1] + wsred[2] + wsred[3];
        float tq = wsred[4] + wsred[5] + wsred[6] + wsred[7];
        float mu = t / (float)SD;
        float var = tq / (float)SD - mu * mu;
        stats[b * 2] = mu;
        stats[b * 2 + 1] = rsqrtf(var + EPSF);
    }
}

// ---------------- ln1 -> q,k,v in bf16, layout [bh][SP][8]; scale*log2e folded into q ----------------
__global__ void k_qkv(const float* __restrict__ tokens, const float* __restrict__ stats,
                      const float* __restrict__ g1, const float* __restrict__ be1,
                      const float* __restrict__ wq, const float* __restrict__ bq,
                      const float* __restrict__ wk, const float* __restrict__ bk,
                      const float* __restrict__ wv, const float* __restrict__ bv,
                      short* __restrict__ qb, short* __restrict__ kb, short* __restrict__ vb) {
    int b = blockIdx.y, bx = blockIdx.x, tid = threadIdx.x;
    __shared__ float xs[4][DD];
    float mu = stats[b * 2];
    float rsig = stats[b * 2 + 1];
    int r = tid >> 6, d = tid & 63;
    int srow = bx * 4 + r;
    if (srow < SS) {
        float t = tokens[((size_t)b * SS + srow) * DD + d];
        xs[r][d] = (t - mu) * rsig * g1[srow * DD + d] + be1[srow * DD + d];
    }
    __syncthreads();
    for (int o = tid; o < 768; o += 256) {
        int rr = o / 192;
        int rem = o % 192;
        int which = rem / 64;       // 0=q 1=k 2=v
        int he = rem % 64;
        int h = he >> 3, e = he & 7;
        int s2 = bx * 4 + rr;
        if (s2 >= SS) continue;
        const float* w = (which == 0) ? wq : (which == 1) ? wk : wv;
        const float* bias = (which == 0) ? bq : (which == 1) ? bk : bv;
        float acc = bias[he];
#pragma unroll
        for (int dd = 0; dd < 8; ++dd)
            acc += xs[rr][h * 8 + dd] * w[(h * 8 + dd) * 8 + e];
        if (which == 0) acc *= SCALE_LOG2E;
        short* dst = (which == 0) ? qb : (which == 1) ? kb : vb;
        dst[((size_t)(b * HH + h) * SP + s2) * 8 + e] = f2bf(acc);
    }
    if (bx == NTB - 1) {
        // zero K pad rows [SS, SP) for all heads of this batch: (SP-SS)*HH*8 = 15872 shorts
        for (int i = tid; i < (SP - SS) * HH * 8; i += 256) {
            int rr = i / (HH * 8);          // pad row index 0..30
            int he = i % (HH * 8);
            int hh = he >> 3, e = he & 7;
            kb[((size_t)(b * HH + hh) * SP + SS + rr) * 8 + e] = 0;
        }
    }
}

// ---------------- MFMA flash attention; CLS-row output + ln2 stats + FUSED final head ----------------
// R22 structure (best-measured 46.2 µs): grid (3, HH, BB), 24 slots, fused
//   run_tiles<3>/<2>, launch_bounds(512,4), no SWP (R21 regression lesson: source
//   rotation costs 16 v_mov/iter; AMDGPU has no modulo scheduling).
// R23: k_final MERGED via last-block pattern — after the stat atomicAdds, each block
//   does threadfence (release) + atomicAdd(cnt2[b]); the 24th block per batch acquires
//   and runs ln2(row0)->MLP->head->softmax on tid<64, reusing dead Es scratch. Saves
//   one dispatch + gap; final work overlaps other batches' attn tails. Release/acquire:
//   each writer's out0/stat stores are fenced before its counter RMW; the last block
//   fences after reading 23 before loading out0/sum2 (G16-safe, device-scope atomics).
#define PACK_PV(s0, s1, o, vf) do { \
    unsigned p0_ = cvt_pk_bf16(exp2_fast((s0)[0]), exp2_fast((s0)[1])); \
    unsigned p1_ = cvt_pk_bf16(exp2_fast((s0)[2]), exp2_fast((s0)[3])); \
    unsigned p2_ = cvt_pk_bf16(exp2_fast((s1)[0]), exp2_fast((s1)[1])); \
    unsigned p3_ = cvt_pk_bf16(exp2_fast((s1)[2]), exp2_fast((s1)[3])); \
    u32x4 pu_ = {p0_, p1_, p2_, p3_}; \
    (o) = __builtin_amdgcn_mfma_f32_16x16x32_bf16(__builtin_bit_cast(bf16x8, pu_), (vf), (o), 0, 0, 0); \
} while (0)

template<int NT>
__device__ __forceinline__ void run_tiles(
    int slot, const short* __restrict__ qb, size_t bhSP,
    const short* kp0, int kstep, int koff16, const short* vbase_l,
    float* Ef, const float* __restrict__ tokens, float* __restrict__ out0,
    int b, int h, int lane, int col, int quad, float& lsum, float& lssq)
{
    const f32x4 zz = {0.f, 0.f, 0.f, 0.f};
    bf16x8 z8 = {0, 0, 0, 0, 0, 0, 0, 0};
    bf16x8 qf[NT];
    f32x4 o[NT];
#pragma unroll
    for (int t = 0; t < NT; ++t) {
        qf[t] = z8;
        if (quad == 0)
            qf[t] = *(const bf16x8*)(qb + (bhSP + (size_t)((slot + QSTR * t) * 16 + col)) * 8);
        o[t] = zz;
    }
    const short* kptr = kp0;
    bf16x8 ka = *(const bf16x8*)kptr;
    bf16x8 kbx = *(const bf16x8*)(kptr + koff16);
    kptr += kstep;
    const short* vptr = vbase_l;
#pragma clang loop unroll(disable)
    for (int ch = 0; ch < NCH; ++ch) {
        bf16x8 vf = *(const bf16x8*)vptr;            // the ONLY LDS op in the loop
        vptr += 32;
        f32x4 s0[NT], s1[NT];
#pragma unroll
        for (int t = 0; t < NT; ++t) {
            s0[t] = __builtin_amdgcn_mfma_f32_16x16x32_bf16(ka, qf[t], zz, 0, 0, 0);
            s1[t] = __builtin_amdgcn_mfma_f32_16x16x32_bf16(kbx, qf[t], zz, 0, 0, 0);
        }
        ka = *(const bf16x8*)kptr;                   // rotated prefetch (dead-load on last
        kbx = *(const bf16x8*)(kptr + koff16);       //  iter lands in adjacent ws region)
        kptr += kstep;
#pragma unroll
        for (int t = 0; t < NT; ++t) PACK_PV(s0[t], s1[t], o[t], vf);
    }
#pragma unroll
    for (int t = 0; t < NT; ++t) {
        int qt = slot + QSTR * t;
        // epilogue: spill O via per-wave scratch (col 8 = softmax denom l).
        // lane(col,quad) holds O[q=4*quad+r][e=col].
#pragma unroll
        for (int r = 0; r < 4; ++r) Ef[(quad * 4 + r) * 16 + col] = o[t][r];
#pragma unroll
        for (int pass = 0; pass < 2; ++pass) {
            int idx = lane + pass * 64;    // 16q x 8e
            int qq = idx >> 3, e = idx & 7;
            int qg = qt * 16 + qq;
            if (qg < SS) {
                float num = Ef[qq * 16 + e];
                float l = Ef[qq * 16 + 8];
                float ov = tokens[((size_t)b * SS + qg) * DD + h * 8 + e] + num / l;
                lsum += ov; lssq += ov * ov;
                if (qg == 0) out0[b * DD + h * 8 + e] = ov;
            }
        }
    }
}

__global__ __launch_bounds__(512, 4)
void k_attn(const short* __restrict__ qb, const short* __restrict__ kb, const short* __restrict__ vb,
            const float* __restrict__ tokens, float* __restrict__ out0,
            float* __restrict__ sum2, float* __restrict__ sumsq2, unsigned* __restrict__ cnt2,
            const float* __restrict__ g2, const float* __restrict__ be2,
            const float* __restrict__ w_enc, const float* __restrict__ b_enc,
            const float* __restrict__ w_out, const float* __restrict__ b_out,
            float* __restrict__ out) {
    __shared__ __align__(16) short VTs[9 * VTROW];   // 19152 B: V^T rows [e][perm-idx]; row 8 = ones(t<SS)
    __shared__ __align__(16) float Es[8 * 256];      // 8192 B: per-wave O spill; reused for reductions/final
    __shared__ int lastFlag;
    int h = blockIdx.y, b = blockIdx.z;
    int bh = b * HH + h;
    int tid = threadIdx.x;
    int wave = tid >> 6, lane = tid & 63;
    int col = lane & 15, quad = lane >> 4;

    {   // stage V^T k-permuted: VTs[e][32*ch + v] = V[32*ch + sigmaPV(v)][e].
        // row 8 = softmax-denominator ones (0 where t >= SS: excludes pad P=1 terms).
        const bf16x8* vg = (const bf16x8*)(vb + (size_t)bh * SP * 8);
        for (int i = tid; i < SP; i += 512) {
            int t = (i & ~31) | sigmaPV(i & 31);
            if (t < SS) {
                bf16x8 row = vg[t];
#pragma unroll
                for (int e = 0; e < 8; ++e) VTs[e * VTROW + i] = row[e];
                VTs[8 * VTROW + i] = (short)0x3F80;   // bf16 1.0
            } else {
#pragma unroll
                for (int e = 0; e < 9; ++e) VTs[e * VTROW + i] = 0;
            }
        }
    }
    __syncthreads();

    // K A-frag straight from global: quad0 lanes walk rows t0+col / t0+col+16;
    // quads 1-3 read the zeroed pad row (same address across lanes -> broadcast).
    const short* kg = kb + (size_t)bh * SP * 8;
    const short* kp0 = kg + ((quad == 0) ? col * 8 : ZROW * 8);
    const int kstep = (quad == 0) ? 256 : 0;     // shorts per 32-t chunk
    const int koff16 = (quad == 0) ? 128 : 0;
    // V B-frag: lane col -> VT row e; cols 9-15 read the ones row (their O columns
    // are computed but never read in the epilogue — harmless finite values)
    const short* vbase_l = VTs + (col < 9 ? col : 8) * VTROW + quad * 8;
    float* Ef = Es + wave * 256;

    float lsum = 0.f, lssq = 0.f;
    int slot = blockIdx.x * 8 + wave;   // 0..23
    size_t bhSP = (size_t)bh * SP;

    if (slot + 2 * QSTR < NQT)    // slots 0-16: 3 tiles fused; slots 17-23: 2 tiles
        run_tiles<3>(slot, qb, bhSP, kp0, kstep, koff16, vbase_l, Ef, tokens, out0,
                     b, h, lane, col, quad, lsum, lssq);
    else
        run_tiles<2>(slot, qb, bhSP, kp0, kstep, koff16, vbase_l, Ef, tokens, out0,
                     b, h, lane, col, quad, lsum, lssq);

    __syncthreads();
    Es[tid] = lsum; Es[512 + tid] = lssq;    // per-wave scratch dead; reuse for reduction
    __syncthreads();
    for (int off = 256; off > 0; off >>= 1) {
        if (tid < off) { Es[tid] += Es[tid + off]; Es[512 + tid] += Es[512 + tid + off]; }
        __syncthreads();
    }
    if (tid == 0) {
        atomicAdd(&sum2[b], Es[0]);
        atomicAdd(&sumsq2[b], Es[512]);
        __threadfence();                              // release: out0 + stat adds visible
        unsigned done = atomicAdd(&cnt2[b], 1u);
        lastFlag = (done == (unsigned)(ABLK - 1));
    }
    __syncthreads();
    if (lastFlag) {
        // ---- fused k_final for batch b (last of the 24 blocks; tid<64 active) ----
        __threadfence();                              // acquire: see all 23 peers' writes
        float* xn = Es;                               // Es dead; reuse 64+64+OUTD floats
        float* hsh = Es + 64;
        float* logit = Es + 128;
        float n = (float)SD;
        float mu = sum2[b] / n;
        float var = sumsq2[b] / n - mu * mu;
        float rs = rsqrtf(var + EPSF);
        float o = 0.f;
        if (tid < 64) {
            o = out0[b * DD + tid];
            xn[tid] = (o - mu) * rs * g2[tid] + be2[tid];
        }
        __syncthreads();
        if (tid < 64) {
            float acc = b_enc[tid];
#pragma unroll
            for (int d = 0; d < DD; ++d) acc += xn[d] * w_enc[d * DD + tid];
            hsh[tid] = o + fmaxf(acc, 0.f);
        }
        __syncthreads();
        if (tid < OUTD) {
            float a = b_out[tid];
#pragma unroll
            for (int d = 0; d < DD; ++d) a += hsh[d] * w_out[d * OUTD + tid];
            logit[tid] = a;
        }
        __syncthreads();
        if (tid == 0) {
            float m = logit[0];
            for (int i = 1; i < OUTD; ++i) m = fmaxf(m, logit[i]);
            float p[OUTD]; float ssum = 0.f;
            for (int i = 0; i < OUTD; ++i) { p[i] = expf(logit[i] - m); ssum += p[i]; }
            for (int i = 0; i < OUTD; ++i) out[b * OUTD + i] = p[i] / ssum;
        }
    }
}

extern "C" void kernel_launch(void* const* d_in, const int* in_sizes, int n_in,
                              void* d_out, int out_size, void* d_ws, size_t ws_size,
                              hipStream_t stream) {
    const float* images = (const float*)d_in[0];
    const float* w_map  = (const float*)d_in[1];
    const float* b_map  = (const float*)d_in[2];
    const float* cls    = (const float*)d_in[3];
    const float* g1     = (const float*)d_in[4];
    const float* be1    = (const float*)d_in[5];
    const float* wq     = (const float*)d_in[6];
    const float* bq     = (const float*)d_in[7];
    const float* wk     = (const float*)d_in[8];
    const float* bk     = (const float*)d_in[9];
    const float* wv     = (const float*)d_in[10];
    const float* bv     = (const float*)d_in[11];
    const float* g2     = (const float*)d_in[12];
    const float* be2    = (const float*)d_in[13];
    const float* w_enc  = (const float*)d_in[14];
    const float* b_enc  = (const float*)d_in[15];
    const float* w_out  = (const float*)d_in[16];
    const float* b_out  = (const float*)d_in[17];
    float* out = (float*)d_out;

    float* ws = (float*)d_ws;
    size_t off = 0;
    float* tokens = ws + off; off += (size_t)BB * SD;
    float* out0   = ws + off; off += BB * DD;
    float* part1  = ws + off; off += BB * NTB;
    float* partq1 = ws + off; off += BB * NTB;
    float* sum2   = ws + off; off += BB;
    float* sumsq2 = ws + off; off += BB;
    float* stats  = ws + off; off += 2 * BB;
    unsigned* cnt2 = (unsigned*)(ws + off); off += BB;
    short* qb = (short*)(ws + off); off += (size_t)BB * HH * SP * 8 / 2;
    short* kb = (short*)(ws + off); off += (size_t)BB * HH * SP * 8 / 2;
    short* vb = (short*)(ws + off); off += (size_t)BB * HH * SP * 8 / 2;

    k_tokens<<<dim3(NTB, BB), 256, 0, stream>>>(images, w_map, b_map, cls, tokens,
                                                part1, partq1, sum2, sumsq2, cnt2);
    k_stats<<<BB, 256, 0, stream>>>(part1, partq1, stats);
    k_qkv<<<dim3(NTB, BB), 256, 0, stream>>>(tokens, stats, g1, be1,
                                             wq, bq, wk, bk, wv, bv, qb, kb, vb);
    k_attn<<<dim3(3, HH, BB), 512, 0, stream>>>(qb, kb, vb, tokens, out0, sum2, sumsq2, cnt2,
                                                g2, be2, w_enc, b_enc, w_out, b_out, out);
}

// Round 13
// 161.764 us; speedup vs baseline: 1.3442x; 1.3442x over previous
//
#include <hip/hip_runtime.h>
#include <math.h>

#define BB 32
#define SS 1025
#define DD 64
#define HH 8
#define IN_D 8
#define NPATCH 1024
#define OUTD 9
#define EPSF 1e-5f
#define SD (SS*DD)        // 65600
#define SP 1056           // padded seq = 33*32
#define NQT 65            // ceil(1025/16) q-tiles
#define NCH 33            // 1056/32 t-chunks
#define VTROW 1064        // VT LDS row stride (shorts)
#define NTB 257           // blocks per batch for token/stat kernels
#define ZROW 1055         // guaranteed-zero K row (pad, zeroed by k_qkv)
#define QSTR 24           // q-tile stride between a slot's tiles (24 slots, grid 3)
#define LOG2_1E4 13.287712379549449f

typedef __attribute__((ext_vector_type(8))) short bf16x8;
typedef __attribute__((ext_vector_type(4))) float f32x4;
typedef __attribute__((ext_vector_type(4))) unsigned u32x4;

// fold softmax scale 1/sqrt(8) and exp->exp2 into Q
#define SCALE_LOG2E (0.35355339059327378f * 1.4426950408889634f)

#if __has_builtin(__builtin_amdgcn_exp2f)
__device__ __forceinline__ float exp2_fast(float x) { return __builtin_amdgcn_exp2f(x); }
#else
__device__ __forceinline__ float exp2_fast(float x) {
    float r; asm("v_exp_f32 %0, %1" : "=v"(r) : "v"(x)); return r;
}
#endif

__device__ __forceinline__ short f2bf(float f) {
    union { float f; unsigned u; } a; a.f = f;
    unsigned r = a.u + 0x7FFFu + ((a.u >> 16) & 1u);  // RNE
    return (short)(r >> 16);
}

// packed f32->bf16 (RNE); lo lands in the LOW short — matches A-frag short order.
__device__ __forceinline__ unsigned cvt_pk_bf16(float lo, float hi) {
    unsigned r;
    asm("v_cvt_pk_bf16_f32 %0, %1, %2" : "=v"(r) : "v"(lo), "v"(hi));
    return r;
}

// PV virtual-k permutation: for A-frag slot v = 8*quad + j, the P value the lane
// already holds in registers is S^T tile row t = 4*quad + (j&3) + 16*(j>>2).
// sigma(v) = bit-shuffle {b2,b4,b3,b1,b0} — bijective on [0,32). V is staged with
// the same permutation so A and B agree on k-order (MFMA k-order is arbitrary).
__device__ __forceinline__ int sigmaPV(int v) {
    return ((v & 24) >> 1) | (v & 3) | ((v & 4) << 2);
}

// ---------------- tokens = [cls; patches@w_map+b_map] + pos; per-block partial ln1 stats ----------------
// R21 (kept): powf libcall -> exp2 identity: 10000^x = exp2(x*log2(1e4)); same
//   overflow->inf->recip-0 path. Worth ~5 µs across 8224 blocks.
__global__ void k_tokens(const float* __restrict__ images, const float* __restrict__ w_map,
                         const float* __restrict__ b_map, const float* __restrict__ cls,
                         float* __restrict__ tokens, float* __restrict__ part1,
                         float* __restrict__ partq1, float* __restrict__ sum2,
                         float* __restrict__ sumsq2) {
    int b = blockIdx.y;
    int bx = blockIdx.x;
    int idx = bx * 256 + threadIdx.x;   // [0, SD)
    int tid = threadIdx.x;
    __shared__ float recip[64];
    __shared__ float wsred[8];
    if (tid < 64) {
        int j = tid;
        float div;
        if ((j & 1) == 0)
            div = exp2_fast((float)j * (LOG2_1E4 / 64.0f));
        else  // reference: 10000^(j-1)/64; overflow->inf -> recip 0 -> arg 0 -> cos=1 (matches f64)
            div = exp2_fast((float)(j - 1) * LOG2_1E4) * (1.0f / 64.0f);
        recip[j] = 1.0f / div;
    }
    __syncthreads();
    float lv = 0.f, lvv = 0.f;
    if (idx < SD) {
        int s = idx >> 6, j = idx & 63;
        float arg = (float)s * recip[j];
        float pv = (j & 1) ? __cosf(arg) : __sinf(arg);
        float v;
        if (s == 0) {
            v = cls[j];
        } else {
            const float* p = images + (size_t)b * (NPATCH * IN_D) + (size_t)(s - 1) * IN_D;
            float acc = b_map[j];
#pragma unroll
            for (int i = 0; i < IN_D; ++i) acc += p[i] * w_map[i * DD + j];
            v = acc;
        }
        v += pv;
        tokens[(size_t)b * SD + idx] = v;
        lv = v; lvv = v * v;
    }
    // wave64 shuffle reduce, then cross-wave combine (1 barrier)
    for (int off = 32; off > 0; off >>= 1) {
        lv += __shfl_down(lv, off, 64);
        lvv += __shfl_down(lvv, off, 64);
    }
    int wv = tid >> 6, ln = tid & 63;
    if (ln == 0) { wsred[wv] = lv; wsred[4 + wv] = lvv; }
    __syncthreads();
    if (tid == 0)  part1[b * NTB + bx]  = wsred[0] + wsred[1] + wsred[2] + wsred[3];
    if (tid == 64) partq1[b * NTB + bx] = wsred[4] + wsred[5] + wsred[6] + wsred[7];
    if (bx == 0) {          // zero the ln2 stat accumulators (k_attn adds later; stream-ordered)
        if (tid == 0) sum2[b] = 0.f;
        if (tid == 1) sumsq2[b] = 0.f;
    }
}

// ---------------- reduce ln1 partials once per batch ----------------
__global__ void k_stats(const float* __restrict__ part1, const float* __restrict__ partq1,
                        float* __restrict__ stats) {
    int b = blockIdx.x, tid = threadIdx.x;   // 256 thr
    float s = 0.f, ss = 0.f;
    for (int i = tid; i < NTB; i += 256) { s += part1[b * NTB + i]; ss += partq1[b * NTB + i]; }
    for (int off = 32; off > 0; off >>= 1) {
        s += __shfl_down(s, off, 64);
        ss += __shfl_down(ss, off, 64);
    }
    __shared__ float wsred[8];
    int wv = tid >> 6, ln = tid & 63;
    if (ln == 0) { wsred[wv] = s; wsred[4 + wv] = ss; }
    __syncthreads();
    if (tid == 0) {
        float t  = wsred[0] + wsred[1] + wsred[2] + wsred[3];
        float tq = wsred[4] + wsred[5] + wsred[6] + wsred[7];
        float mu = t / (float)SD;
        float var = tq / (float)SD - mu * mu;
        stats[b * 2] = mu;
        stats[b * 2 + 1] = rsqrtf(var + EPSF);
    }
}

// ---------------- ln1 -> q,k,v in bf16, layout [bh][SP][8]; scale*log2e folded into q ----------------
__global__ void k_qkv(const float* __restrict__ tokens, const float* __restrict__ stats,
                      const float* __restrict__ g1, const float* __restrict__ be1,
                      const float* __restrict__ wq, const float* __restrict__ bq,
                      const float* __restrict__ wk, const float* __restrict__ bk,
                      const float* __restrict__ wv, const float* __restrict__ bv,
                      short* __restrict__ qb, short* __restrict__ kb, short* __restrict__ vb) {
    int b = blockIdx.y, bx = blockIdx.x, tid = threadIdx.x;
    __shared__ float xs[4][DD];
    float mu = stats[b * 2];
    float rsig = stats[b * 2 + 1];
    int r = tid >> 6, d = tid & 63;
    int srow = bx * 4 + r;
    if (srow < SS) {
        float t = tokens[((size_t)b * SS + srow) * DD + d];
        xs[r][d] = (t - mu) * rsig * g1[srow * DD + d] + be1[srow * DD + d];
    }
    __syncthreads();
    for (int o = tid; o < 768; o += 256) {
        int rr = o / 192;
        int rem = o % 192;
        int which = rem / 64;       // 0=q 1=k 2=v
        int he = rem % 64;
        int h = he >> 3, e = he & 7;
        int s2 = bx * 4 + rr;
        if (s2 >= SS) continue;
        const float* w = (which == 0) ? wq : (which == 1) ? wk : wv;
        const float* bias = (which == 0) ? bq : (which == 1) ? bk : bv;
        float acc = bias[he];
#pragma unroll
        for (int dd = 0; dd < 8; ++dd)
            acc += xs[rr][h * 8 + dd] * w[(h * 8 + dd) * 8 + e];
        if (which == 0) acc *= SCALE_LOG2E;
        short* dst = (which == 0) ? qb : (which == 1) ? kb : vb;
        dst[((size_t)(b * HH + h) * SP + s2) * 8 + e] = f2bf(acc);
    }
    if (bx == NTB - 1) {
        // zero K pad rows [SS, SP) for all heads of this batch: (SP-SS)*HH*8 = 15872 shorts
        for (int i = tid; i < (SP - SS) * HH * 8; i += 256) {
            int rr = i / (HH * 8);          // pad row index 0..30
            int he = i % (HH * 8);
            int hh = he >> 3, e = he & 7;
            kb[((size_t)(b * HH + hh) * SP + SS + rr) * 8 + e] = 0;
        }
    }
}

// ---------------- MFMA flash attention; CLS-row output + ln2-stat accumulation ----------------
// R24: REVERT to R22 exactly (best-measured composition: 163.6 µs total, k_attn 46.2).
//   R23 lesson: last-block fusion of k_final regressed k_attn 46->111 µs with UNCHANGED
//   FETCH/WRITE/conflicts — per-block __threadfence() (device-scope: buffer_wbl2 + inv,
//   a full L2 writeback pass) x768 blocks disrupts the per-XCD L2 that feeds every
//   other block's K-stream. Pure stall, no extra HBM traffic. Device-scope release
//   fences are NOT cheap-once-per-block at 768 blocks when the inner loop lives on
//   L2-hit bandwidth. Dispatch saving ~5 µs vs ~64 µs cost. Reverted.
// Structure: grid (3, HH, BB), 24 slots, fused run_tiles<3> (slots 0-16) / <2> (17-23),
//   launch_bounds(512,4), no SWP.
//   R21 lesson: source-level SWP costs 16 v_mov/iter (no modulo scheduling on AMDGPU).
//   R20 lesson: occupancy 45->54% at same perf — the ~46 µs floor is the per-wave
//   MFMA->exp->cvt->PV chain + mem-stall residue, not wave count.
// History: R12 swapped-operand QK^T (P register-local, 1 ds_read/chunk); R15/R16 spill
//   killed (launch_bounds(512,4) + unroll(disable) + branchless rotated prefetch);
//   R18 pairing (+11%); R19 full tile-set fusion (+6%).
#define PACK_PV(s0, s1, o, vf) do { \
    unsigned p0_ = cvt_pk_bf16(exp2_fast((s0)[0]), exp2_fast((s0)[1])); \
    unsigned p1_ = cvt_pk_bf16(exp2_fast((s0)[2]), exp2_fast((s0)[3])); \
    unsigned p2_ = cvt_pk_bf16(exp2_fast((s1)[0]), exp2_fast((s1)[1])); \
    unsigned p3_ = cvt_pk_bf16(exp2_fast((s1)[2]), exp2_fast((s1)[3])); \
    u32x4 pu_ = {p0_, p1_, p2_, p3_}; \
    (o) = __builtin_amdgcn_mfma_f32_16x16x32_bf16(__builtin_bit_cast(bf16x8, pu_), (vf), (o), 0, 0, 0); \
} while (0)

template<int NT>
__device__ __forceinline__ void run_tiles(
    int slot, const short* __restrict__ qb, size_t bhSP,
    const short* kp0, int kstep, int koff16, const short* vbase_l,
    float* Ef, const float* __restrict__ tokens, float* __restrict__ out0,
    int b, int h, int lane, int col, int quad, float& lsum, float& lssq)
{
    const f32x4 zz = {0.f, 0.f, 0.f, 0.f};
    bf16x8 z8 = {0, 0, 0, 0, 0, 0, 0, 0};
    bf16x8 qf[NT];
    f32x4 o[NT];
#pragma unroll
    for (int t = 0; t < NT; ++t) {
        qf[t] = z8;
        if (quad == 0)
            qf[t] = *(const bf16x8*)(qb + (bhSP + (size_t)((slot + QSTR * t) * 16 + col)) * 8);
        o[t] = zz;
    }
    const short* kptr = kp0;
    bf16x8 ka = *(const bf16x8*)kptr;
    bf16x8 kbx = *(const bf16x8*)(kptr + koff16);
    kptr += kstep;
    const short* vptr = vbase_l;
#pragma clang loop unroll(disable)
    for (int ch = 0; ch < NCH; ++ch) {
        bf16x8 vf = *(const bf16x8*)vptr;            // the ONLY LDS op in the loop
        vptr += 32;
        f32x4 s0[NT], s1[NT];
#pragma unroll
        for (int t = 0; t < NT; ++t) {
            s0[t] = __builtin_amdgcn_mfma_f32_16x16x32_bf16(ka, qf[t], zz, 0, 0, 0);
            s1[t] = __builtin_amdgcn_mfma_f32_16x16x32_bf16(kbx, qf[t], zz, 0, 0, 0);
        }
        ka = *(const bf16x8*)kptr;                   // rotated prefetch (dead-load on last
        kbx = *(const bf16x8*)(kptr + koff16);       //  iter lands in adjacent ws region)
        kptr += kstep;
#pragma unroll
        for (int t = 0; t < NT; ++t) PACK_PV(s0[t], s1[t], o[t], vf);
    }
#pragma unroll
    for (int t = 0; t < NT; ++t) {
        int qt = slot + QSTR * t;
        // epilogue: spill O via per-wave scratch (col 8 = softmax denom l).
        // lane(col,quad) holds O[q=4*quad+r][e=col].
#pragma unroll
        for (int r = 0; r < 4; ++r) Ef[(quad * 4 + r) * 16 + col] = o[t][r];
#pragma unroll
        for (int pass = 0; pass < 2; ++pass) {
            int idx = lane + pass * 64;    // 16q x 8e
            int qq = idx >> 3, e = idx & 7;
            int qg = qt * 16 + qq;
            if (qg < SS) {
                float num = Ef[qq * 16 + e];
                float l = Ef[qq * 16 + 8];
                float ov = tokens[((size_t)b * SS + qg) * DD + h * 8 + e] + num / l;
                lsum += ov; lssq += ov * ov;
                if (qg == 0) out0[b * DD + h * 8 + e] = ov;
            }
        }
    }
}

__global__ __launch_bounds__(512, 4)
void k_attn(const short* __restrict__ qb, const short* __restrict__ kb, const short* __restrict__ vb,
            const float* __restrict__ tokens, float* __restrict__ out0,
            float* __restrict__ sum2, float* __restrict__ sumsq2) {
    __shared__ __align__(16) short VTs[9 * VTROW];   // 19152 B: V^T rows [e][perm-idx]; row 8 = ones(t<SS)
    __shared__ __align__(16) float Es[8 * 256];      // 8192 B: per-wave O spill; reused for final reduction
    int h = blockIdx.y, b = blockIdx.z;
    int bh = b * HH + h;
    int tid = threadIdx.x;
    int wave = tid >> 6, lane = tid & 63;
    int col = lane & 15, quad = lane >> 4;

    {   // stage V^T k-permuted: VTs[e][32*ch + v] = V[32*ch + sigmaPV(v)][e].
        // row 8 = softmax-denominator ones (0 where t >= SS: excludes pad P=1 terms).
        const bf16x8* vg = (const bf16x8*)(vb + (size_t)bh * SP * 8);
        for (int i = tid; i < SP; i += 512) {
            int t = (i & ~31) | sigmaPV(i & 31);
            if (t < SS) {
                bf16x8 row = vg[t];
#pragma unroll
                for (int e = 0; e < 8; ++e) VTs[e * VTROW + i] = row[e];
                VTs[8 * VTROW + i] = (short)0x3F80;   // bf16 1.0
            } else {
#pragma unroll
                for (int e = 0; e < 9; ++e) VTs[e * VTROW + i] = 0;
            }
        }
    }
    __syncthreads();

    // K A-frag straight from global: quad0 lanes walk rows t0+col / t0+col+16;
    // quads 1-3 read the zeroed pad row (same address across lanes -> broadcast).
    const short* kg = kb + (size_t)bh * SP * 8;
    const short* kp0 = kg + ((quad == 0) ? col * 8 : ZROW * 8);
    const int kstep = (quad == 0) ? 256 : 0;     // shorts per 32-t chunk
    const int koff16 = (quad == 0) ? 128 : 0;
    // V B-frag: lane col -> VT row e; cols 9-15 read the ones row (their O columns
    // are computed but never read in the epilogue — harmless finite values)
    const short* vbase_l = VTs + (col < 9 ? col : 8) * VTROW + quad * 8;
    float* Ef = Es + wave * 256;

    float lsum = 0.f, lssq = 0.f;
    int slot = blockIdx.x * 8 + wave;   // 0..23
    size_t bhSP = (size_t)bh * SP;

    if (slot + 2 * QSTR < NQT)    // slots 0-16: 3 tiles fused; slots 17-23: 2 tiles
        run_tiles<3>(slot, qb, bhSP, kp0, kstep, koff16, vbase_l, Ef, tokens, out0,
                     b, h, lane, col, quad, lsum, lssq);
    else
        run_tiles<2>(slot, qb, bhSP, kp0, kstep, koff16, vbase_l, Ef, tokens, out0,
                     b, h, lane, col, quad, lsum, lssq);

    __syncthreads();
    Es[tid] = lsum; Es[512 + tid] = lssq;    // per-wave scratch dead; reuse for reduction
    __syncthreads();
    for (int off = 256; off > 0; off >>= 1) {
        if (tid < off) { Es[tid] += Es[tid + off]; Es[512 + tid] += Es[512 + tid + off]; }
        __syncthreads();
    }
    if (tid == 0) {
        atomicAdd(&sum2[b], Es[0]);
        atomicAdd(&sumsq2[b], Es[512]);
    }
}

// ---------------- final: ln2(row0) -> MLP(+relu) -> residual -> head -> softmax ----------------
__global__ void k_final(const float* __restrict__ out0, const float* __restrict__ sum2,
                        const float* __restrict__ sumsq2, const float* __restrict__ g2,
                        const float* __restrict__ be2, const float* __restrict__ w_enc,
                        const float* __restrict__ b_enc, const float* __restrict__ w_out,
                        const float* __restrict__ b_out, float* __restrict__ out) {
    int b = blockIdx.x;
    int tid = threadIdx.x;  // 64
    __shared__ float xn[DD], hsh[DD], logit[OUTD];
    float n = (float)SD;
    float mu = sum2[b] / n;
    float var = sumsq2[b] / n - mu * mu;
    float rs = rsqrtf(var + EPSF);
    float o = out0[b * DD + tid];
    xn[tid] = (o - mu) * rs * g2[tid] + be2[tid];
    __syncthreads();
    float acc = b_enc[tid];
#pragma unroll
    for (int d = 0; d < DD; ++d) acc += xn[d] * w_enc[d * DD + tid];
    hsh[tid] = o + fmaxf(acc, 0.f);
    __syncthreads();
    if (tid < OUTD) {
        float a = b_out[tid];
#pragma unroll
        for (int d = 0; d < DD; ++d) a += hsh[d] * w_out[d * OUTD + tid];
        logit[tid] = a;
    }
    __syncthreads();
    if (tid == 0) {
        float m = logit[0];
        for (int i = 1; i < OUTD; ++i) m = fmaxf(m, logit[i]);
        float p[OUTD]; float ssum = 0.f;
        for (int i = 0; i < OUTD; ++i) { p[i] = expf(logit[i] - m); ssum += p[i]; }
        for (int i = 0; i < OUTD; ++i) out[b * OUTD + i] = p[i] / ssum;
    }
}

extern "C" void kernel_launch(void* const* d_in, const int* in_sizes, int n_in,
                              void* d_out, int out_size, void* d_ws, size_t ws_size,
                              hipStream_t stream) {
    const float* images = (const float*)d_in[0];
    const float* w_map  = (const float*)d_in[1];
    const float* b_map  = (const float*)d_in[2];
    const float* cls    = (const float*)d_in[3];
    const float* g1     = (const float*)d_in[4];
    const float* be1    = (const float*)d_in[5];
    const float* wq     = (const float*)d_in[6];
    const float* bq     = (const float*)d_in[7];
    const float* wk     = (const float*)d_in[8];
    const float* bk     = (const float*)d_in[9];
    const float* wv     = (const float*)d_in[10];
    const float* bv     = (const float*)d_in[11];
    const float* g2     = (const float*)d_in[12];
    const float* be2    = (const float*)d_in[13];
    const float* w_enc  = (const float*)d_in[14];
    const float* b_enc  = (const float*)d_in[15];
    const float* w_out  = (const float*)d_in[16];
    const float* b_out  = (const float*)d_in[17];
    float* out = (float*)d_out;

    float* ws = (float*)d_ws;
    size_t off = 0;
    float* tokens = ws + off; off += (size_t)BB * SD;
    float* out0   = ws + off; off += BB * DD;
    float* part1  = ws + off; off += BB * NTB;
    float* partq1 = ws + off; off += BB * NTB;
    float* sum2   = ws + off; off += BB;
    float* sumsq2 = ws + off; off += BB;
    float* stats  = ws + off; off += 2 * BB;
    short* qb = (short*)(ws + off); off += (size_t)BB * HH * SP * 8 / 2;
    short* kb = (short*)(ws + off); off += (size_t)BB * HH * SP * 8 / 2;
    short* vb = (short*)(ws + off); off += (size_t)BB * HH * SP * 8 / 2;

    k_tokens<<<dim3(NTB, BB), 256, 0, stream>>>(images, w_map, b_map, cls, tokens,
                                                part1, partq1, sum2, sumsq2);
    k_stats<<<BB, 256, 0, stream>>>(part1, partq1, stats);
    k_qkv<<<dim3(NTB, BB), 256, 0, stream>>>(tokens, stats, g1, be1,
                                             wq, bq, wk, bk, wv, bv, qb, kb, vb);
    k_attn<<<dim3(3, HH, BB), 512, 0, stream>>>(qb, kb, vb, tokens, out0, sum2, sumsq2);
    k_final<<<BB, DD, 0, stream>>>(out0, sum2, sumsq2, g2, be2, w_enc, b_enc, w_out, b_out, out);
}